// Round 3
// baseline (662.266 us; speedup 1.0000x reference)
//
#include <hip/hip_runtime.h>
#include <hip/hip_bf16.h>
#include <stdint.h>

typedef __attribute__((ext_vector_type(8))) short short8;
typedef __attribute__((ext_vector_type(4))) float f32x4;
typedef __attribute__((ext_vector_type(4))) unsigned short us4;

#define SEQ_L 2048
#define NHEADS 16
#define HD 64
#define DMODEL 1024
#define NB 4

__device__ __forceinline__ short f2bf(float f) {
  unsigned int x = __float_as_uint(f);
  x += 0x7fffu + ((x >> 16) & 1u);   // RNE
  return (short)(x >> 16);
}

__device__ __forceinline__ float fast_exp2(float x) {
#if __has_builtin(__builtin_amdgcn_exp2f)
  return __builtin_amdgcn_exp2f(x);
#else
  return exp2f(x);
#endif
}

__device__ __forceinline__ void gload16(const void* g, void* l) {
  __builtin_amdgcn_global_load_lds(
      (const __attribute__((address_space(1))) unsigned char*)g,
      (__attribute__((address_space(3))) unsigned char*)l, 16, 0, 0);
}

// ---------------- fp32 -> bf16 conversion (memory-bound, vectorized) --------
__global__ void f32_to_bf16_kernel(const float* __restrict__ src,
                                   short* __restrict__ dst, int n) {
  int i = (blockIdx.x * 256 + threadIdx.x) * 4;
  if (i >= n) return;
  float4 f = *reinterpret_cast<const float4*>(src + i);
  us4 o;
  o[0] = (unsigned short)f2bf(f.x);
  o[1] = (unsigned short)f2bf(f.y);
  o[2] = (unsigned short)f2bf(f.z);
  o[3] = (unsigned short)f2bf(f.w);
  *reinterpret_cast<us4*>(dst + i) = o;
}

// ---------------- GEMM: C[M,N] = A[M,K] * W[N,K]^T  (both K-major) ----------
template <int EPI>
__global__ void gemm_bt(const short* __restrict__ A, const short* __restrict__ W,
                        const float* __restrict__ bias, void* __restrict__ Cout,
                        int K, float oscale) {
  const int tid = threadIdx.x;
  const int w = tid >> 6, l = tid & 63;
  const int tm = blockIdx.x * 128;
  const int tn = blockIdx.y * 128;
  const int wm = (w >> 1) * 64, wn = (w & 1) * 64;
  __shared__ short As[2][128 * 32];
  __shared__ short Bs[2][128 * 32];

  const int srow = w * 32 + (l >> 2);
  const int scol = (l & 3) * 8;
  const short* pa0 = A + (size_t)(tm + srow) * K + scol;
  const short* pa1 = pa0 + (size_t)16 * K;
  const short* pb0 = W + (size_t)(tn + srow) * K + scol;
  const short* pb1 = pb0 + (size_t)16 * K;
  const int ldst = w * 1024 + l * 8;

  gload16(pa0, &As[0][ldst]);
  gload16(pa1, &As[0][ldst + 512]);
  gload16(pb0, &Bs[0][ldst]);
  gload16(pb1, &Bs[0][ldst + 512]);

  f32x4 acc[4][4];
#pragma unroll
  for (int i = 0; i < 4; ++i)
#pragma unroll
    for (int j = 0; j < 4; ++j) acc[i][j] = (f32x4){0.f, 0.f, 0.f, 0.f};

  const int lr = l >> 4, lc = l & 15;
  const int nt = K / 32;
  int cur = 0;
  __syncthreads();
  for (int t = 0; t < nt; ++t) {
    if (t + 1 < nt) {
      int ko = (t + 1) * 32;
      gload16(pa0 + ko, &As[cur ^ 1][ldst]);
      gload16(pa1 + ko, &As[cur ^ 1][ldst + 512]);
      gload16(pb0 + ko, &Bs[cur ^ 1][ldst]);
      gload16(pb1 + ko, &Bs[cur ^ 1][ldst + 512]);
    }
    short8 af[4], bfv[4];
#pragma unroll
    for (int i = 0; i < 4; ++i)
      af[i] = *reinterpret_cast<const short8*>(
          &As[cur][(wm + i * 16 + lc) * 32 + lr * 8]);
#pragma unroll
    for (int j = 0; j < 4; ++j)
      bfv[j] = *reinterpret_cast<const short8*>(
          &Bs[cur][(wn + j * 16 + lc) * 32 + lr * 8]);
#pragma unroll
    for (int i = 0; i < 4; ++i)
#pragma unroll
      for (int j = 0; j < 4; ++j)
        acc[i][j] =
            __builtin_amdgcn_mfma_f32_16x16x32_bf16(af[i], bfv[j], acc[i][j], 0, 0, 0);
    __syncthreads();
    cur ^= 1;
  }

  if (EPI == 0) {
    short* O = (short*)Cout;
#pragma unroll
    for (int j = 0; j < 4; ++j) {
      int col = tn + wn + j * 16 + lc;
      float bv = bias[col];
      int h = col >> 6, d = col & 63;
#pragma unroll
      for (int i = 0; i < 4; ++i)
#pragma unroll
        for (int r = 0; r < 4; ++r) {
          int row = tm + wm + i * 16 + lr * 4 + r;
          int b = row >> 11, pos = row & 2047;
          float v = (acc[i][j][r] + bv) * oscale;
          O[(((size_t)(b * NHEADS + h) * SEQ_L + pos) << 6) + d] = f2bf(v);
        }
    }
  } else {
    float* O = (float*)Cout;
#pragma unroll
    for (int j = 0; j < 4; ++j) {
      int col = tn + wn + j * 16 + lc;
      float bv = bias[col];
#pragma unroll
      for (int i = 0; i < 4; ++i)
#pragma unroll
        for (int r = 0; r < 4; ++r) {
          int row = tm + wm + i * 16 + lr * 4 + r;
          O[(size_t)row * DMODEL + col] = acc[i][j][r] + bv;
        }
    }
  }
}

// ---------------- flash attention -------------------------------------------
// 1D grid 1024, XCD swizzle (16 q-tiles of a bh share an XCD's L2).
// 4 waves, QBLK=128, KBLK=64. LDS 40KB -> 4 blocks/CU (grid = exactly 4*256).
// K double-buffered via global_load_lds; V reg-prefetched, single LDS buffer
// (write-late behind a barrier). Row-sum via ones-MFMA; softmax in exp2 domain
// (log2e folded into q-scale).
__global__ __launch_bounds__(256, 4) void attn_fwd(
    const short* __restrict__ Qh, const short* __restrict__ Kh,
    const short* __restrict__ Vh, const int* __restrict__ mask,
    short* __restrict__ O) {
  const int tid = threadIdx.x;
  const int w = tid >> 6, l = tid & 63;
  const int bid = blockIdx.x;
  const int bh = (bid & 7) | ((bid >> 7) << 3);  // bid%8 == bh%8 -> XCD-stable
  const int qt = (bid >> 3) & 15;
  const int b = bh >> 4, h = bh & 15;
  const short* q = Qh + (size_t)bh * SEQ_L * HD;
  const short* k = Kh + (size_t)bh * SEQ_L * HD;
  const short* v = Vh + (size_t)bh * SEQ_L * HD;
  const int* mrow = mask + b * SEQ_L;
  const int qbase = qt * 128;

  __shared__ short QP[128 * 64];   // Q staging, then P tile (per-wave regions)
  __shared__ short KT[2][64 * 64];
  __shared__ short VT[64 * 64];    // V^T : [d][k], single buffer

  auto sw = [](int row, int e) { return row * 64 + (e ^ ((row & 7) << 3)); };

  // stage Q via global_load_lds: linear dest, inverse-swizzled source
#pragma unroll
  for (int qi = 0; qi < 4; ++qi) {
    int c = w * 4 + qi;
    int row = c * 8 + (l >> 3);
    int ss = (l & 7) ^ (l >> 3);
    gload16(q + (size_t)(qbase + row) * HD + ss * 8, &QP[c * 512 + l * 8]);
  }

  const int lr = l >> 4, lc = l & 15;

  short8 va, vb;
  auto stageK = [&](int kb, int buf) {
#pragma unroll
    for (int qi = 0; qi < 2; ++qi) {
      int c = w * 2 + qi;
      int row = c * 8 + (l >> 3);
      int ss = (l & 7) ^ (l >> 3);
      gload16(k + (size_t)(kb + row) * HD + ss * 8, &KT[buf][c * 512 + l * 8]);
    }
  };
  auto loadV = [&](int kb) {
    const short* vp = v + (size_t)(kb + l) * HD + w * 16;
    va = *reinterpret_cast<const short8*>(vp);
    vb = *reinterpret_cast<const short8*>(vp + 8);
  };
  auto writeV = [&]() {
#pragma unroll
    for (int e = 0; e < 8; ++e) {
      VT[sw(w * 16 + e, l)] = va[e];
      VT[sw(w * 16 + 8 + e, l)] = vb[e];
    }
  };

  // ones B-fragment for the row-sum MFMA (all lanes: 8x bf16 1.0)
  short8 ones;
#pragma unroll
  for (int e = 0; e < 8; ++e) ones[e] = (short)0x3F80;

  // prologue
  stageK(0, 0);
  loadV(0);
  writeV();
  __syncthreads();

  short8 qf[2][2];
#pragma unroll
  for (int i = 0; i < 2; ++i)
#pragma unroll
    for (int s = 0; s < 2; ++s)
      qf[i][s] = *reinterpret_cast<const short8*>(
          &QP[sw(w * 32 + i * 16 + lc, s * 32 + lr * 8)]);

  float m_st[2][4];
  f32x4 acc_o[2][4], acc_sum[2];
#pragma unroll
  for (int i = 0; i < 2; ++i) {
#pragma unroll
    for (int r = 0; r < 4; ++r) m_st[i][r] = -3.0e38f;
    acc_sum[i] = (f32x4){0.f, 0.f, 0.f, 0.f};
#pragma unroll
    for (int j = 0; j < 4; ++j) acc_o[i][j] = (f32x4){0.f, 0.f, 0.f, 0.f};
  }

  int cur = 0;
  const int NT = SEQ_L / 64;
  for (int ic = 0; ic < NT; ++ic) {
    const int kb = ic * 64;
    const bool pf = (ic + 1 < NT);
    if (pf) {                       // prefetch next chunk (issue-early)
      stageK(kb + 64, cur ^ 1);
      loadV(kb + 64);
    }

    float mb[4];
#pragma unroll
    for (int j = 0; j < 4; ++j)
      mb[j] = mrow[kb + j * 16 + lc] ? 0.f : -__builtin_inff();

    // S = Q K^T (scale*log2e folded into Q) + mask bias
    f32x4 s_acc[2][4];
#pragma unroll
    for (int i = 0; i < 2; ++i)
#pragma unroll
      for (int j = 0; j < 4; ++j) s_acc[i][j] = (f32x4){0.f, 0.f, 0.f, 0.f};
    __builtin_amdgcn_s_setprio(1);
#pragma unroll
    for (int s = 0; s < 2; ++s) {
      short8 kf[4];
#pragma unroll
      for (int j = 0; j < 4; ++j)
        kf[j] = *reinterpret_cast<const short8*>(
            &KT[cur][sw(j * 16 + lc, s * 32 + lr * 8)]);
#pragma unroll
      for (int i = 0; i < 2; ++i)
#pragma unroll
        for (int j = 0; j < 4; ++j)
          s_acc[i][j] =
              __builtin_amdgcn_mfma_f32_16x16x32_bf16(qf[i][s], kf[j], s_acc[i][j], 0, 0, 0);
    }
    __builtin_amdgcn_s_setprio(0);
#pragma unroll
    for (int i = 0; i < 2; ++i)
#pragma unroll
      for (int j = 0; j < 4; ++j)
#pragma unroll
        for (int r = 0; r < 4; ++r) s_acc[i][j][r] += mb[j];

    // online softmax max (rows live in 16-lane groups)
    float mnew[2][4], sc[2][4];
#pragma unroll
    for (int i = 0; i < 2; ++i)
#pragma unroll
      for (int r = 0; r < 4; ++r) {
        float mx = fmaxf(fmaxf(s_acc[i][0][r], s_acc[i][1][r]),
                         fmaxf(s_acc[i][2][r], s_acc[i][3][r]));
        for (int d = 1; d < 16; d <<= 1) mx = fmaxf(mx, __shfl_xor(mx, d, 64));
        mx = fmaxf(mx, m_st[i][r]);
        sc[i][r] = (m_st[i][r] == mx) ? 1.f : fast_exp2(m_st[i][r] - mx);
        mnew[i][r] = mx;
        m_st[i][r] = mx;
      }
    // P = exp2(S - m), write swizzled to per-wave P region
#pragma unroll
    for (int i = 0; i < 2; ++i)
#pragma unroll
      for (int j = 0; j < 4; ++j)
#pragma unroll
        for (int r = 0; r < 4; ++r) {
          float p = fast_exp2(s_acc[i][j][r] - mnew[i][r]);
          QP[sw(w * 32 + i * 16 + lr * 4 + r, j * 16 + lc)] = f2bf(p);
        }
    // rescale accumulators (sum accumulates with same rescale -> final l)
#pragma unroll
    for (int i = 0; i < 2; ++i) {
#pragma unroll
      for (int r = 0; r < 4; ++r) acc_sum[i][r] *= sc[i][r];
#pragma unroll
      for (int j = 0; j < 4; ++j)
#pragma unroll
        for (int r = 0; r < 4; ++r) acc_o[i][j][r] *= sc[i][r];
    }

    // O += P V ; l += P . 1   (P region is wave-private -> no barrier)
    __builtin_amdgcn_s_setprio(1);
#pragma unroll
    for (int s = 0; s < 2; ++s) {
      short8 pf2[2], vf[4];
#pragma unroll
      for (int i = 0; i < 2; ++i)
        pf2[i] = *reinterpret_cast<const short8*>(
            &QP[sw(w * 32 + i * 16 + lc, s * 32 + lr * 8)]);
#pragma unroll
      for (int j = 0; j < 4; ++j)
        vf[j] = *reinterpret_cast<const short8*>(
            &VT[sw(j * 16 + lc, s * 32 + lr * 8)]);
#pragma unroll
      for (int i = 0; i < 2; ++i) {
#pragma unroll
        for (int j = 0; j < 4; ++j)
          acc_o[i][j] =
              __builtin_amdgcn_mfma_f32_16x16x32_bf16(pf2[i], vf[j], acc_o[i][j], 0, 0, 0);
        acc_sum[i] =
            __builtin_amdgcn_mfma_f32_16x16x32_bf16(pf2[i], ones, acc_sum[i], 0, 0, 0);
      }
    }
    __builtin_amdgcn_s_setprio(0);

    __syncthreads();            // all waves done reading VT/KT[cur]
    if (pf) {
      writeV();                 // overwrite single V buffer
      __syncthreads();          // V writes visible before next iteration
    }
    cur ^= 1;
  }

  // epilogue: O / l, bf16, [B, Q, D] layout for the output projection
#pragma unroll
  for (int i = 0; i < 2; ++i)
#pragma unroll
    for (int j = 0; j < 4; ++j)
#pragma unroll
      for (int r = 0; r < 4; ++r) {
        int row = qbase + w * 32 + i * 16 + lr * 4 + r;
        int d = j * 16 + lc;
        float ov = acc_o[i][j][r] / acc_sum[i][r];
        O[(size_t)(b * SEQ_L + row) * DMODEL + h * HD + d] = f2bf(ov);
      }
}

// ---------------- launch ----------------------------------------------------
extern "C" void kernel_launch(void* const* d_in, const int* in_sizes, int n_in,
                              void* d_out, int out_size, void* d_ws, size_t ws_size,
                              hipStream_t stream) {
  (void)in_sizes; (void)n_in; (void)out_size; (void)ws_size;
  const float* x  = (const float*)d_in[0];
  const float* y  = (const float*)d_in[1];
  const int* mask = (const int*)d_in[2];
  const float* Wq = (const float*)d_in[3];
  const float* bq = (const float*)d_in[4];
  const float* Wk = (const float*)d_in[5];
  const float* bk = (const float*)d_in[6];
  const float* Wv = (const float*)d_in[7];
  const float* bv = (const float*)d_in[8];
  const float* Wo = (const float*)d_in[9];
  const float* bo = (const float*)d_in[10];
  float* out = (float*)d_out;

  const size_t MQ = (size_t)NB * SEQ_L;
  const size_t TOK = MQ * DMODEL;
  const size_t TOKB = TOK * 2;
  const size_t WB = (size_t)DMODEL * DMODEL * 2;

  char* ws = (char*)d_ws;
  short* xb  = (short*)ws;            ws += TOKB;
  short* yb  = (short*)ws;            ws += TOKB;
  short* wqb = (short*)ws;            ws += WB;
  short* wkb = (short*)ws;            ws += WB;
  short* wvb = (short*)ws;            ws += WB;
  short* wob = (short*)ws;            ws += WB;
  short* qh  = (short*)ws;            ws += TOKB;
  short* kh  = (short*)ws;            ws += TOKB;
  short* vh  = (short*)ws;            ws += TOKB;
  short* attnb = xb;                  // alias: xb dead after q projection

  const int W2 = DMODEL * DMODEL;
  f32_to_bf16_kernel<<<dim3((unsigned)(TOK / 1024)), 256, 0, stream>>>(x, xb, (int)TOK);
  f32_to_bf16_kernel<<<dim3((unsigned)(TOK / 1024)), 256, 0, stream>>>(y, yb, (int)TOK);
  f32_to_bf16_kernel<<<dim3(W2 / 1024), 256, 0, stream>>>(Wq, wqb, W2);
  f32_to_bf16_kernel<<<dim3(W2 / 1024), 256, 0, stream>>>(Wk, wkb, W2);
  f32_to_bf16_kernel<<<dim3(W2 / 1024), 256, 0, stream>>>(Wv, wvb, W2);
  f32_to_bf16_kernel<<<dim3(W2 / 1024), 256, 0, stream>>>(Wo, wob, W2);

  dim3 ggrid(64, 8);
  const float qscale = 0.125f * 1.44269504089f;  // 1/sqrt(64) * log2(e)
  gemm_bt<0><<<ggrid, 256, 0, stream>>>(xb, wqb, bq, qh, DMODEL, qscale);
  gemm_bt<0><<<ggrid, 256, 0, stream>>>(yb, wkb, bk, kh, DMODEL, 1.0f);
  gemm_bt<0><<<ggrid, 256, 0, stream>>>(yb, wvb, bv, vh, DMODEL, 1.0f);

  attn_fwd<<<dim3(1024), 256, 0, stream>>>(qh, kh, vh, mask, attnb);

  gemm_bt<1><<<ggrid, 256, 0, stream>>>(attnb, wob, bo, out, DMODEL, 1.0f);
}

// Round 4
// 526.108 us; speedup vs baseline: 1.2588x; 1.2588x over previous
//
#include <hip/hip_runtime.h>
#include <hip/hip_bf16.h>
#include <stdint.h>

typedef __attribute__((ext_vector_type(8))) short short8;
typedef __attribute__((ext_vector_type(4))) float f32x4;
typedef __attribute__((ext_vector_type(4))) unsigned short us4;

#define SEQ_L 2048
#define NHEADS 16
#define HD 64
#define DMODEL 1024
#define NB 4

__device__ __forceinline__ short f2bf(float f) {
  unsigned int x = __float_as_uint(f);
  x += 0x7fffu + ((x >> 16) & 1u);   // RNE
  return (short)(x >> 16);
}

__device__ __forceinline__ float fast_exp2(float x) {
#if __has_builtin(__builtin_amdgcn_exp2f)
  return __builtin_amdgcn_exp2f(x);
#else
  return exp2f(x);
#endif
}

__device__ __forceinline__ void gload16(const void* g, void* l) {
  __builtin_amdgcn_global_load_lds(
      (const __attribute__((address_space(1))) unsigned char*)g,
      (__attribute__((address_space(3))) unsigned char*)l, 16, 0, 0);
}

// ---------------- fp32 -> bf16 conversion (memory-bound, vectorized) --------
__global__ void f32_to_bf16_kernel(const float* __restrict__ src,
                                   short* __restrict__ dst, int n) {
  int i = (blockIdx.x * 256 + threadIdx.x) * 4;
  if (i >= n) return;
  float4 f = *reinterpret_cast<const float4*>(src + i);
  us4 o;
  o[0] = (unsigned short)f2bf(f.x);
  o[1] = (unsigned short)f2bf(f.y);
  o[2] = (unsigned short)f2bf(f.z);
  o[3] = (unsigned short)f2bf(f.w);
  *reinterpret_cast<us4*>(dst + i) = o;
}

// ---------------- GEMM: C[M,N] = A[M,K] * W[N,K]^T  (both K-major) ----------
template <int EPI>
__global__ void gemm_bt(const short* __restrict__ A, const short* __restrict__ W,
                        const float* __restrict__ bias, void* __restrict__ Cout,
                        int K, float oscale) {
  const int tid = threadIdx.x;
  const int w = tid >> 6, l = tid & 63;
  const int tm = blockIdx.x * 128;
  const int tn = blockIdx.y * 128;
  const int wm = (w >> 1) * 64, wn = (w & 1) * 64;
  __shared__ short As[2][128 * 32];
  __shared__ short Bs[2][128 * 32];

  const int srow = w * 32 + (l >> 2);
  const int scol = (l & 3) * 8;
  const short* pa0 = A + (size_t)(tm + srow) * K + scol;
  const short* pa1 = pa0 + (size_t)16 * K;
  const short* pb0 = W + (size_t)(tn + srow) * K + scol;
  const short* pb1 = pb0 + (size_t)16 * K;
  const int ldst = w * 1024 + l * 8;

  gload16(pa0, &As[0][ldst]);
  gload16(pa1, &As[0][ldst + 512]);
  gload16(pb0, &Bs[0][ldst]);
  gload16(pb1, &Bs[0][ldst + 512]);

  f32x4 acc[4][4];
#pragma unroll
  for (int i = 0; i < 4; ++i)
#pragma unroll
    for (int j = 0; j < 4; ++j) acc[i][j] = (f32x4){0.f, 0.f, 0.f, 0.f};

  const int lr = l >> 4, lc = l & 15;
  const int nt = K / 32;
  int cur = 0;
  __syncthreads();
  for (int t = 0; t < nt; ++t) {
    if (t + 1 < nt) {
      int ko = (t + 1) * 32;
      gload16(pa0 + ko, &As[cur ^ 1][ldst]);
      gload16(pa1 + ko, &As[cur ^ 1][ldst + 512]);
      gload16(pb0 + ko, &Bs[cur ^ 1][ldst]);
      gload16(pb1 + ko, &Bs[cur ^ 1][ldst + 512]);
    }
    short8 af[4], bfv[4];
#pragma unroll
    for (int i = 0; i < 4; ++i)
      af[i] = *reinterpret_cast<const short8*>(
          &As[cur][(wm + i * 16 + lc) * 32 + lr * 8]);
#pragma unroll
    for (int j = 0; j < 4; ++j)
      bfv[j] = *reinterpret_cast<const short8*>(
          &Bs[cur][(wn + j * 16 + lc) * 32 + lr * 8]);
#pragma unroll
    for (int i = 0; i < 4; ++i)
#pragma unroll
      for (int j = 0; j < 4; ++j)
        acc[i][j] =
            __builtin_amdgcn_mfma_f32_16x16x32_bf16(af[i], bfv[j], acc[i][j], 0, 0, 0);
    __syncthreads();
    cur ^= 1;
  }

  if (EPI == 0) {
    short* O = (short*)Cout;
#pragma unroll
    for (int j = 0; j < 4; ++j) {
      int col = tn + wn + j * 16 + lc;
      float bv = bias[col];
      int h = col >> 6, d = col & 63;
#pragma unroll
      for (int i = 0; i < 4; ++i)
#pragma unroll
        for (int r = 0; r < 4; ++r) {
          int row = tm + wm + i * 16 + lr * 4 + r;
          int b = row >> 11, pos = row & 2047;
          float v = (acc[i][j][r] + bv) * oscale;
          O[(((size_t)(b * NHEADS + h) * SEQ_L + pos) << 6) + d] = f2bf(v);
        }
    }
  } else {
    float* O = (float*)Cout;
#pragma unroll
    for (int j = 0; j < 4; ++j) {
      int col = tn + wn + j * 16 + lc;
      float bv = bias[col];
#pragma unroll
      for (int i = 0; i < 4; ++i)
#pragma unroll
        for (int r = 0; r < 4; ++r) {
          int row = tm + wm + i * 16 + lr * 4 + r;
          O[(size_t)row * DMODEL + col] = acc[i][j][r] + bv;
        }
    }
  }
}

// ---------------- flash attention -------------------------------------------
// 1D grid 1024, XCD swizzle. 4 waves, QBLK=128, KBLK=64. LDS 40KB -> 4
// blocks/CU, grid exactly 4*256 resident (no tail). Per-i split of
// QK^T/softmax/P-write halves s_acc peak pressure so 128-reg budget fits
// (round-3 spilled: 854MB scratch writes at VGPR cap). Row-sum via ones-MFMA;
// exp2-domain softmax.
__global__ __launch_bounds__(256, 4) void attn_fwd(
    const short* __restrict__ Qh, const short* __restrict__ Kh,
    const short* __restrict__ Vh, const int* __restrict__ mask,
    short* __restrict__ O) {
  const int tid = threadIdx.x;
  const int w = tid >> 6, l = tid & 63;
  const int bid = blockIdx.x;
  const int bh = (bid & 7) | ((bid >> 7) << 3);  // bid%8 == bh%8 -> XCD-stable
  const int qt = (bid >> 3) & 15;
  const int b = bh >> 4, h = bh & 15;
  const short* q = Qh + (size_t)bh * SEQ_L * HD;
  const short* k = Kh + (size_t)bh * SEQ_L * HD;
  const short* v = Vh + (size_t)bh * SEQ_L * HD;
  const int* mrow = mask + b * SEQ_L;
  const int qbase = qt * 128;

  __shared__ short QP[128 * 64];   // Q staging, then P tile (per-wave regions)
  __shared__ short KT[2][64 * 64];
  __shared__ short VT[64 * 64];    // V^T : [d][k], single buffer

  auto sw = [](int row, int e) { return row * 64 + (e ^ ((row & 7) << 3)); };

  // stage Q via global_load_lds: linear dest, inverse-swizzled source
#pragma unroll
  for (int qi = 0; qi < 4; ++qi) {
    int c = w * 4 + qi;
    int row = c * 8 + (l >> 3);
    int ss = (l & 7) ^ (l >> 3);
    gload16(q + (size_t)(qbase + row) * HD + ss * 8, &QP[c * 512 + l * 8]);
  }

  const int lr = l >> 4, lc = l & 15;

  short8 va, vb;
  auto stageK = [&](int kb, int buf) {
#pragma unroll
    for (int qi = 0; qi < 2; ++qi) {
      int c = w * 2 + qi;
      int row = c * 8 + (l >> 3);
      int ss = (l & 7) ^ (l >> 3);
      gload16(k + (size_t)(kb + row) * HD + ss * 8, &KT[buf][c * 512 + l * 8]);
    }
  };
  auto loadV = [&](int kb) {
    const short* vp = v + (size_t)(kb + l) * HD + w * 16;
    va = *reinterpret_cast<const short8*>(vp);
    vb = *reinterpret_cast<const short8*>(vp + 8);
  };
  auto writeV = [&]() {
#pragma unroll
    for (int e = 0; e < 8; ++e) {
      VT[sw(w * 16 + e, l)] = va[e];
      VT[sw(w * 16 + 8 + e, l)] = vb[e];
    }
  };

  // prologue
  stageK(0, 0);
  loadV(0);
  writeV();
  __syncthreads();

  short8 qf[2][2];
#pragma unroll
  for (int i = 0; i < 2; ++i)
#pragma unroll
    for (int s = 0; s < 2; ++s)
      qf[i][s] = *reinterpret_cast<const short8*>(
          &QP[sw(w * 32 + i * 16 + lc, s * 32 + lr * 8)]);

  float m_st[2][4];
  f32x4 acc_o[2][4], acc_sum[2];
#pragma unroll
  for (int i = 0; i < 2; ++i) {
#pragma unroll
    for (int r = 0; r < 4; ++r) m_st[i][r] = -3.0e38f;
    acc_sum[i] = (f32x4){0.f, 0.f, 0.f, 0.f};
#pragma unroll
    for (int j = 0; j < 4; ++j) acc_o[i][j] = (f32x4){0.f, 0.f, 0.f, 0.f};
  }

  int cur = 0;
  const int NT = SEQ_L / 64;
  for (int ic = 0; ic < NT; ++ic) {
    const int kb = ic * 64;
    const bool pf = (ic + 1 < NT);
    if (pf) stageK(kb + 64, cur ^ 1);   // K prefetch (direct to LDS, no regs)

    float mb[4];
#pragma unroll
    for (int j = 0; j < 4; ++j)
      mb[j] = mrow[kb + j * 16 + lc] ? 0.f : -__builtin_inff();

    // per-i: QK^T -> softmax -> P-write  (keeps s_acc lifetime to 16 regs)
#pragma unroll
    for (int i = 0; i < 2; ++i) {
      f32x4 s_acc[4];
#pragma unroll
      for (int j = 0; j < 4; ++j) s_acc[j] = (f32x4){0.f, 0.f, 0.f, 0.f};
      __builtin_amdgcn_s_setprio(1);
#pragma unroll
      for (int s = 0; s < 2; ++s) {
        short8 kf[4];
#pragma unroll
        for (int j = 0; j < 4; ++j)
          kf[j] = *reinterpret_cast<const short8*>(
              &KT[cur][sw(j * 16 + lc, s * 32 + lr * 8)]);
#pragma unroll
        for (int j = 0; j < 4; ++j)
          s_acc[j] =
              __builtin_amdgcn_mfma_f32_16x16x32_bf16(qf[i][s], kf[j], s_acc[j], 0, 0, 0);
      }
      __builtin_amdgcn_s_setprio(0);
#pragma unroll
      for (int j = 0; j < 4; ++j)
#pragma unroll
        for (int r = 0; r < 4; ++r) s_acc[j][r] += mb[j];

      float sc[4];
#pragma unroll
      for (int r = 0; r < 4; ++r) {
        float mx = fmaxf(fmaxf(s_acc[0][r], s_acc[1][r]),
                         fmaxf(s_acc[2][r], s_acc[3][r]));
        for (int d = 1; d < 16; d <<= 1) mx = fmaxf(mx, __shfl_xor(mx, d, 64));
        mx = fmaxf(mx, m_st[i][r]);
        sc[r] = (m_st[i][r] == mx) ? 1.f : fast_exp2(m_st[i][r] - mx);
        // P = exp2(S - mx) row r
#pragma unroll
        for (int j = 0; j < 4; ++j) {
          float p = fast_exp2(s_acc[j][r] - mx);
          QP[sw(w * 32 + i * 16 + lr * 4 + r, j * 16 + lc)] = f2bf(p);
        }
        m_st[i][r] = mx;
      }
      // rescale accumulators
#pragma unroll
      for (int r = 0; r < 4; ++r) acc_sum[i][r] *= sc[r];
#pragma unroll
      for (int j = 0; j < 4; ++j)
#pragma unroll
        for (int r = 0; r < 4; ++r) acc_o[i][j][r] *= sc[r];
      __builtin_amdgcn_sched_barrier(0);  // pin i-lifetime split (regalloc)
    }

    if (pf) loadV(kb + 64);  // V prefetch into regs (consumed after barrier)

    // O += P V ; l += P . 1   (P region is wave-private -> no barrier)
    short8 ones;
#pragma unroll
    for (int e = 0; e < 8; ++e) ones[e] = (short)0x3F80;
    __builtin_amdgcn_s_setprio(1);
#pragma unroll
    for (int s = 0; s < 2; ++s) {
      short8 vf[4];
#pragma unroll
      for (int j = 0; j < 4; ++j)
        vf[j] = *reinterpret_cast<const short8*>(
            &VT[sw(j * 16 + lc, s * 32 + lr * 8)]);
#pragma unroll
      for (int i = 0; i < 2; ++i) {
        short8 pf2 = *reinterpret_cast<const short8*>(
            &QP[sw(w * 32 + i * 16 + lc, s * 32 + lr * 8)]);
#pragma unroll
        for (int j = 0; j < 4; ++j)
          acc_o[i][j] =
              __builtin_amdgcn_mfma_f32_16x16x32_bf16(pf2, vf[j], acc_o[i][j], 0, 0, 0);
        acc_sum[i] =
            __builtin_amdgcn_mfma_f32_16x16x32_bf16(pf2, ones, acc_sum[i], 0, 0, 0);
      }
    }
    __builtin_amdgcn_s_setprio(0);

    __syncthreads();            // all waves done reading VT/KT[cur]
    if (pf) {
      writeV();                 // overwrite single V buffer
      __syncthreads();          // V writes visible before next iteration
    }
    cur ^= 1;
  }

  // epilogue: O / l, bf16, [B, Q, D] layout for the output projection
#pragma unroll
  for (int i = 0; i < 2; ++i)
#pragma unroll
    for (int j = 0; j < 4; ++j)
#pragma unroll
      for (int r = 0; r < 4; ++r) {
        int row = qbase + w * 32 + i * 16 + lr * 4 + r;
        int d = j * 16 + lc;
        float ov = acc_o[i][j][r] / acc_sum[i][r];
        O[(size_t)(b * SEQ_L + row) * DMODEL + h * HD + d] = f2bf(ov);
      }
}

// ---------------- launch ----------------------------------------------------
extern "C" void kernel_launch(void* const* d_in, const int* in_sizes, int n_in,
                              void* d_out, int out_size, void* d_ws, size_t ws_size,
                              hipStream_t stream) {
  (void)in_sizes; (void)n_in; (void)out_size; (void)ws_size;
  const float* x  = (const float*)d_in[0];
  const float* y  = (const float*)d_in[1];
  const int* mask = (const int*)d_in[2];
  const float* Wq = (const float*)d_in[3];
  const float* bq = (const float*)d_in[4];
  const float* Wk = (const float*)d_in[5];
  const float* bk = (const float*)d_in[6];
  const float* Wv = (const float*)d_in[7];
  const float* bv = (const float*)d_in[8];
  const float* Wo = (const float*)d_in[9];
  const float* bo = (const float*)d_in[10];
  float* out = (float*)d_out;

  const size_t MQ = (size_t)NB * SEQ_L;
  const size_t TOK = MQ * DMODEL;
  const size_t TOKB = TOK * 2;
  const size_t WB = (size_t)DMODEL * DMODEL * 2;

  char* ws = (char*)d_ws;
  short* xb  = (short*)ws;            ws += TOKB;
  short* yb  = (short*)ws;            ws += TOKB;
  short* wqb = (short*)ws;            ws += WB;
  short* wkb = (short*)ws;            ws += WB;
  short* wvb = (short*)ws;            ws += WB;
  short* wob = (short*)ws;            ws += WB;
  short* qh  = (short*)ws;            ws += TOKB;
  short* kh  = (short*)ws;            ws += TOKB;
  short* vh  = (short*)ws;            ws += TOKB;
  short* attnb = xb;                  // alias: xb dead after q projection

  const int W2 = DMODEL * DMODEL;
  f32_to_bf16_kernel<<<dim3((unsigned)(TOK / 1024)), 256, 0, stream>>>(x, xb, (int)TOK);
  f32_to_bf16_kernel<<<dim3((unsigned)(TOK / 1024)), 256, 0, stream>>>(y, yb, (int)TOK);
  f32_to_bf16_kernel<<<dim3(W2 / 1024), 256, 0, stream>>>(Wq, wqb, W2);
  f32_to_bf16_kernel<<<dim3(W2 / 1024), 256, 0, stream>>>(Wk, wkb, W2);
  f32_to_bf16_kernel<<<dim3(W2 / 1024), 256, 0, stream>>>(Wv, wvb, W2);
  f32_to_bf16_kernel<<<dim3(W2 / 1024), 256, 0, stream>>>(Wo, wob, W2);

  dim3 ggrid(64, 8);
  const float qscale = 0.125f * 1.44269504089f;  // 1/sqrt(64) * log2(e)
  gemm_bt<0><<<ggrid, 256, 0, stream>>>(xb, wqb, bq, qh, DMODEL, qscale);
  gemm_bt<0><<<ggrid, 256, 0, stream>>>(yb, wkb, bk, kh, DMODEL, 1.0f);
  gemm_bt<0><<<ggrid, 256, 0, stream>>>(yb, wvb, bv, vh, DMODEL, 1.0f);

  attn_fwd<<<dim3(1024), 256, 0, stream>>>(qh, kh, vh, mask, attnb);

  gemm_bt<1><<<ggrid, 256, 0, stream>>>(attnb, wob, bo, out, DMODEL, 1.0f);
}